// Round 4
// baseline (3984.410 us; speedup 1.0000x reference)
//
#include <hip/hip_runtime.h>
#include <hip/hip_bf16.h>
#include <cstdint>
#include <cstddef>

#define B_ALL 256
#define T_LEN 512
#define D_INP 64
#define HD    128
#define G4    512            // 4*H
#define NC    12
#define BCH   128            // batch per chunk
#define ROWS  (BCH * T_LEN)  // 65536 rows per chunk

// ---------- helpers ----------
__device__ __forceinline__ float bf2f(unsigned short u) {
    union { unsigned int i; float f; } v; v.i = ((unsigned int)u) << 16; return v.f;
}
__device__ __forceinline__ unsigned short f2bf(float f) {
    union { float f; unsigned int i; } v; v.f = f;
    unsigned int r = v.i + 0x7FFFu + ((v.i >> 16) & 1u);  // round-nearest-even
    return (unsigned short)(r >> 16);
}
__device__ __forceinline__ float sigf(float x) { return 1.0f / (1.0f + __expf(-x)); }
__device__ __forceinline__ float tanh_f(float x) {
    float xx = fminf(15.0f, fmaxf(-15.0f, x));
    float e = __expf(2.0f * xx);
    return (e - 1.0f) / (e + 1.0f);
}

__device__ __forceinline__ float4 loadA4(const float* p) { return *(const float4*)p; }
__device__ __forceinline__ float4 loadA4(const unsigned short* p) {
    ushort4 u = *(const ushort4*)p;  // 8B aligned
    return make_float4(bf2f(u.x), bf2f(u.y), bf2f(u.z), bf2f(u.w));
}

// ---------- gates GEMM: out[r][c] = bias[c] + sum_k A[r][k] * W[c][k] ----------
template <typename TA>
__global__ __launch_bounds__(256)
void gates_gemm(const TA* __restrict__ A, const float* __restrict__ W,
                const float* __restrict__ bias, const int* __restrict__ lens,
                unsigned short* __restrict__ out, int K)
{
    int row0 = blockIdx.x * 128;
    int col0 = blockIdx.y * 128;
    int bl = row0 >> 9;            // T_LEN = 512 rows per batch element
    int t0 = row0 & (T_LEN - 1);
    if (t0 >= lens[bl]) return;    // whole tile masked -> never read downstream

    __shared__ float As[32][130];
    __shared__ float Bs[32][130];

    int tid = threadIdx.x;
    int tx = tid & 15;
    int ty = tid >> 4;
    int lr = tid >> 3;
    int lk = (tid & 7) * 4;

    float acc[8][8];
#pragma unroll
    for (int i = 0; i < 8; ++i)
#pragma unroll
        for (int j = 0; j < 8; ++j) acc[i][j] = 0.0f;

    for (int kt = 0; kt < K; kt += 32) {
#pragma unroll
        for (int rr = 0; rr < 128; rr += 32) {
            int r = rr + lr;
            float4 v = loadA4(A + (size_t)(row0 + r) * K + kt + lk);
            As[lk + 0][r] = v.x; As[lk + 1][r] = v.y;
            As[lk + 2][r] = v.z; As[lk + 3][r] = v.w;
        }
#pragma unroll
        for (int rr = 0; rr < 128; rr += 32) {
            int c = rr + lr;
            float4 v = *(const float4*)(W + (size_t)(col0 + c) * K + kt + lk);
            Bs[lk + 0][c] = v.x; Bs[lk + 1][c] = v.y;
            Bs[lk + 2][c] = v.z; Bs[lk + 3][c] = v.w;
        }
        __syncthreads();
#pragma unroll 8
        for (int kk = 0; kk < 32; ++kk) {
            float a[8], b[8];
#pragma unroll
            for (int q = 0; q < 4; ++q) {
                float2 t = *(const float2*)&As[kk][ty * 8 + 2 * q];
                a[2 * q] = t.x; a[2 * q + 1] = t.y;
                float2 u = *(const float2*)&Bs[kk][tx * 8 + 2 * q];
                b[2 * q] = u.x; b[2 * q + 1] = u.y;
            }
#pragma unroll
            for (int i = 0; i < 8; ++i)
#pragma unroll
                for (int j = 0; j < 8; ++j) acc[i][j] += a[i] * b[j];
        }
        __syncthreads();
    }

    float bj[8];
#pragma unroll
    for (int j = 0; j < 8; ++j) bj[j] = bias[col0 + tx * 8 + j];
#pragma unroll
    for (int i = 0; i < 8; ++i) {
        size_t base = (size_t)(row0 + ty * 8 + i) * 1024 + col0 + tx * 8;
        ushort4 p0, p1;
        p0.x = f2bf(acc[i][0] + bj[0]); p0.y = f2bf(acc[i][1] + bj[1]);
        p0.z = f2bf(acc[i][2] + bj[2]); p0.w = f2bf(acc[i][3] + bj[3]);
        p1.x = f2bf(acc[i][4] + bj[4]); p1.y = f2bf(acc[i][5] + bj[5]);
        p1.z = f2bf(acc[i][6] + bj[6]); p1.w = f2bf(acc[i][7] + bj[7]);
        *(ushort4*)&out[base] = p0;
        *(ushort4*)&out[base + 4] = p1;
    }
}

// ---------- LSTM recurrence ----------
// R3 post-mortem: allocator SANK the loop-invariant Whh loads back into the
// loop (occupancy heuristic; VGPR stayed 88) -> per-step 512B/thread L2
// reloads -> L2-throughput-bound (~1800 cyc/step vs 512 VALU floor).
// Fix: 1024 threads/block, thread PAIR per gate row, 64 weights/thread
// (16 named float4s ~= 95 VGPR total, under the natural target -> nothing to
// sink) + amdgpu_waves_per_eu(4,4) pins the pressure target at 128 VGPR.
// Partial dots combine via __shfl_xor(g,1).
#define W_DECL(i) float4 w##i = *(const float4*)(wrow + (i) * 4);
#define W_DOT(i, acc) { float4 h4 = *(const float4*)&hbase[(i) * 4];            \
    acc = fmaf(w##i.x, h4.x, fmaf(w##i.y, h4.y,                                 \
          fmaf(w##i.z, h4.z, fmaf(w##i.w, h4.w, acc)))); }

__global__ __attribute__((amdgpu_waves_per_eu(4, 4))) __launch_bounds__(1024)
void lstm_rec(const unsigned short* __restrict__ xg,   // [ROWS][1024]
              const float* __restrict__ Whh,           // [2][512][128]
              const int* __restrict__ lens,            // chunk-offset
              unsigned short* __restrict__ hs,         // [ROWS][256] or null
              float* __restrict__ hTf, float* __restrict__ hTb,
              int bOff)
{
    int dir = blockIdx.x >> 7;   // 128 batch per chunk
    int bl  = blockIdx.x & 127;
    int L   = lens[bl];
    int tid  = threadIdx.x;
    int j    = tid >> 1;         // gate row 0..511 (pair of lanes per row)
    int half = tid & 1;          // which 64-wide half of the dot

    __shared__ float h_s[HD];
    __shared__ float g_s[G4];

    const float* wrow = Whh + ((size_t)dir * G4 + j) * HD + half * 64;
    W_DECL(0)  W_DECL(1)  W_DECL(2)  W_DECL(3)
    W_DECL(4)  W_DECL(5)  W_DECL(6)  W_DECL(7)
    W_DECL(8)  W_DECL(9)  W_DECL(10) W_DECL(11)
    W_DECL(12) W_DECL(13) W_DECL(14) W_DECL(15)

    if (tid < HD) h_s[tid] = 0.0f;
    float c = 0.0f;
    __syncthreads();

    size_t rowbase = (size_t)(bl * T_LEN) * 1024 + dir * G4 + j;
    int tt = dir ? (L - 1) : 0;
    float xcur = bf2f(xg[rowbase + (size_t)tt * 1024]);  // both halves load same addr (L1 broadcast)

    const float* hbase = h_s + half * 64;

    for (int t = 0; t < L; ++t) {
        // prefetch next step's xg; its L1/L2 latency overlaps the dot product
        int t2  = (t + 1 < L) ? (t + 1) : t;
        int ttn = dir ? (L - 1 - t2) : t2;
        unsigned short xnraw = xg[rowbase + (size_t)ttn * 1024];

        float g0 = half ? 0.0f : xcur, g1 = 0.0f, g2 = 0.0f, g3 = 0.0f;
        W_DOT(0,  g0) W_DOT(1,  g1) W_DOT(2,  g2) W_DOT(3,  g3)
        W_DOT(4,  g0) W_DOT(5,  g1) W_DOT(6,  g2) W_DOT(7,  g3)
        W_DOT(8,  g0) W_DOT(9,  g1) W_DOT(10, g2) W_DOT(11, g3)
        W_DOT(12, g0) W_DOT(13, g1) W_DOT(14, g2) W_DOT(15, g3)
        float gp = (g0 + g1) + (g2 + g3);
        gp += __shfl_xor(gp, 1);     // pair-sum; both lanes now hold full dot
        g_s[j] = gp;                 // identical value from both lanes
        __syncthreads();
        if (tid < HD) {
            float ig = sigf(g_s[tid]);
            float fg = sigf(g_s[tid + 128]);
            float gg = tanh_f(g_s[tid + 256]);
            float og = sigf(g_s[tid + 384]);
            c = fg * c + ig * gg;
            float hn = og * tanh_f(c);
            h_s[tid] = hn;
            if (hs) hs[(size_t)(bl * T_LEN + tt) * 256 + dir * HD + tid] = f2bf(hn);
        }
        __syncthreads();
        xcur = bf2f(xnraw);
        tt = ttn;
    }
    if (hTf && tid < HD) {
        (dir ? hTb : hTf)[(size_t)(bOff + bl) * HD + tid] = h_s[tid];
    }
}

// ---------- final FC + log_softmax: h = [hT_b, hT_f] ----------
__global__ __launch_bounds__(256)
void fc_lsm(const float* __restrict__ hTf, const float* __restrict__ hTb,
            const float* __restrict__ Wfc, const float* __restrict__ bfc,
            float* __restrict__ out)
{
    int b = threadIdx.x;
    const float* hb = hTb + (size_t)b * HD;
    const float* hf = hTf + (size_t)b * HD;
    float l[NC];
#pragma unroll
    for (int cc = 0; cc < NC; ++cc) {
        const float* wr = Wfc + cc * 256;
        float acc = bfc[cc];
        for (int k = 0; k < HD; k += 4) {
            acc += hb[k] * wr[k] + hb[k + 1] * wr[k + 1]
                 + hb[k + 2] * wr[k + 2] + hb[k + 3] * wr[k + 3];
            acc += hf[k] * wr[128 + k] + hf[k + 1] * wr[128 + k + 1]
                 + hf[k + 2] * wr[128 + k + 2] + hf[k + 3] * wr[128 + k + 3];
        }
        l[cc] = acc;
    }
    float m = l[0];
#pragma unroll
    for (int cc = 1; cc < NC; ++cc) m = fmaxf(m, l[cc]);
    float s = 0.0f;
#pragma unroll
    for (int cc = 0; cc < NC; ++cc) s += __expf(l[cc] - m);
    float lg = m + logf(s);
#pragma unroll
    for (int cc = 0; cc < NC; ++cc) out[(size_t)b * NC + cc] = l[cc] - lg;
}

extern "C" void kernel_launch(void* const* d_in, const int* in_sizes, int n_in,
                              void* d_out, int out_size, void* d_ws, size_t ws_size,
                              hipStream_t stream)
{
    const float* X    = (const float*)d_in[0];
    const int*   len  = (const int*)d_in[1];
    const float* Wih0 = (const float*)d_in[2];   // (2,512,64)  -> (1024,64)
    const float* Whh0 = (const float*)d_in[3];   // (2,512,128)
    const float* b0   = (const float*)d_in[4];   // (2,512) -> (1024)
    const float* Wih1 = (const float*)d_in[5];   // (2,512,256) -> (1024,256)
    const float* Whh1 = (const float*)d_in[6];
    const float* b1   = (const float*)d_in[7];
    const float* Wfc  = (const float*)d_in[8];   // (12,256)
    const float* bfc  = (const float*)d_in[9];   // (12)
    float* out = (float*)d_out;

    char* ws = (char*)d_ws;
    unsigned short* xg = (unsigned short*)ws;                              // ROWS*1024 bf16
    unsigned short* h1 = (unsigned short*)(ws + (size_t)ROWS * 1024 * 2);  // ROWS*256 bf16
    float* hTf = (float*)(ws + (size_t)ROWS * 1024 * 2 + (size_t)ROWS * 256 * 2);
    float* hTb = hTf + (size_t)B_ALL * HD;

    dim3 blk(256);
    for (int ch = 0; ch < 2; ++ch) {
        const int* lc = len + ch * BCH;
        const float* Xc = X + (size_t)ch * BCH * T_LEN * D_INP;

        gates_gemm<float><<<dim3(ROWS / 128, 1024 / 128), blk, 0, stream>>>(
            Xc, Wih0, b0, lc, xg, D_INP);
        lstm_rec<<<2 * BCH, 1024, 0, stream>>>(xg, Whh0, lc, h1, nullptr, nullptr, 0);
        gates_gemm<unsigned short><<<dim3(ROWS / 128, 1024 / 128), blk, 0, stream>>>(
            h1, Wih1, b1, lc, xg, 2 * HD);
        lstm_rec<<<2 * BCH, 1024, 0, stream>>>(xg, Whh1, lc, nullptr, hTf, hTb, ch * BCH);
    }
    fc_lsm<<<1, 256, 0, stream>>>(hTf, hTb, Wfc, bfc, out);
}

// Round 5
// 3732.642 us; speedup vs baseline: 1.0675x; 1.0675x over previous
//
#include <hip/hip_runtime.h>
#include <hip/hip_bf16.h>
#include <cstdint>
#include <cstddef>

#define B_ALL 256
#define T_LEN 512
#define D_INP 64
#define HD    128
#define G4    512            // 4*H
#define NC    12
#define BCH   128            // batch per chunk
#define ROWS  (BCH * T_LEN)  // 65536 rows per chunk

// ---------- helpers ----------
__device__ __forceinline__ float bf2f(unsigned short u) {
    union { unsigned int i; float f; } v; v.i = ((unsigned int)u) << 16; return v.f;
}
__device__ __forceinline__ unsigned short f2bf(float f) {
    union { float f; unsigned int i; } v; v.f = f;
    unsigned int r = v.i + 0x7FFFu + ((v.i >> 16) & 1u);  // round-nearest-even
    return (unsigned short)(r >> 16);
}
__device__ __forceinline__ float sigf(float x) { return 1.0f / (1.0f + __expf(-x)); }
__device__ __forceinline__ float tanh_f(float x) {
    float xx = fminf(15.0f, fmaxf(-15.0f, x));
    float e = __expf(2.0f * xx);
    return (e - 1.0f) / (e + 1.0f);
}

__device__ __forceinline__ float4 loadA4(const float* p) { return *(const float4*)p; }
__device__ __forceinline__ float4 loadA4(const unsigned short* p) {
    ushort4 u = *(const ushort4*)p;  // 8B aligned
    return make_float4(bf2f(u.x), bf2f(u.y), bf2f(u.z), bf2f(u.w));
}

// ---------- gates GEMM: out[r][c] = bias[c] + sum_k A[r][k] * W[c][k] ----------
template <typename TA>
__global__ __launch_bounds__(256)
void gates_gemm(const TA* __restrict__ A, const float* __restrict__ W,
                const float* __restrict__ bias, const int* __restrict__ lens,
                unsigned short* __restrict__ out, int K)
{
    int row0 = blockIdx.x * 128;
    int col0 = blockIdx.y * 128;
    int bl = row0 >> 9;            // T_LEN = 512 rows per batch element
    int t0 = row0 & (T_LEN - 1);
    if (t0 >= lens[bl]) return;    // whole tile masked -> never read downstream

    __shared__ float As[32][130];
    __shared__ float Bs[32][130];

    int tid = threadIdx.x;
    int tx = tid & 15;
    int ty = tid >> 4;
    int lr = tid >> 3;
    int lk = (tid & 7) * 4;

    float acc[8][8];
#pragma unroll
    for (int i = 0; i < 8; ++i)
#pragma unroll
        for (int j = 0; j < 8; ++j) acc[i][j] = 0.0f;

    for (int kt = 0; kt < K; kt += 32) {
#pragma unroll
        for (int rr = 0; rr < 128; rr += 32) {
            int r = rr + lr;
            float4 v = loadA4(A + (size_t)(row0 + r) * K + kt + lk);
            As[lk + 0][r] = v.x; As[lk + 1][r] = v.y;
            As[lk + 2][r] = v.z; As[lk + 3][r] = v.w;
        }
#pragma unroll
        for (int rr = 0; rr < 128; rr += 32) {
            int c = rr + lr;
            float4 v = *(const float4*)(W + (size_t)(col0 + c) * K + kt + lk);
            Bs[lk + 0][c] = v.x; Bs[lk + 1][c] = v.y;
            Bs[lk + 2][c] = v.z; Bs[lk + 3][c] = v.w;
        }
        __syncthreads();
#pragma unroll 8
        for (int kk = 0; kk < 32; ++kk) {
            float a[8], b[8];
#pragma unroll
            for (int q = 0; q < 4; ++q) {
                float2 t = *(const float2*)&As[kk][ty * 8 + 2 * q];
                a[2 * q] = t.x; a[2 * q + 1] = t.y;
                float2 u = *(const float2*)&Bs[kk][tx * 8 + 2 * q];
                b[2 * q] = u.x; b[2 * q + 1] = u.y;
            }
#pragma unroll
            for (int i = 0; i < 8; ++i)
#pragma unroll
                for (int j = 0; j < 8; ++j) acc[i][j] += a[i] * b[j];
        }
        __syncthreads();
    }

    float bj[8];
#pragma unroll
    for (int j = 0; j < 8; ++j) bj[j] = bias[col0 + tx * 8 + j];
#pragma unroll
    for (int i = 0; i < 8; ++i) {
        size_t base = (size_t)(row0 + ty * 8 + i) * 1024 + col0 + tx * 8;
        ushort4 p0, p1;
        p0.x = f2bf(acc[i][0] + bj[0]); p0.y = f2bf(acc[i][1] + bj[1]);
        p0.z = f2bf(acc[i][2] + bj[2]); p0.w = f2bf(acc[i][3] + bj[3]);
        p1.x = f2bf(acc[i][4] + bj[4]); p1.y = f2bf(acc[i][5] + bj[5]);
        p1.z = f2bf(acc[i][6] + bj[6]); p1.w = f2bf(acc[i][7] + bj[7]);
        *(ushort4*)&out[base] = p0;
        *(ushort4*)&out[base + 4] = p1;
    }
}

// ---------- LSTM recurrence: one block per (dir, batch-element) ----------
// R4 post-mortem: allocator sank Whh loads in ALL of R1-R4 (VGPR 88/100/88/56);
// FETCH_SIZE 37.6 GB/dispatch == 256 blk x 512 steps x 256 KB reloads -> HBM
// latency-bound. Fix: load the 32 weight-float4s via `asm volatile`
// global_load_dwordx4 -- a volatile asm result CANNOT be rematerialized or
// sunk, so the 128 weight VGPRs are unavoidably live and the scheduler must
// drop its occupancy target instead of reloading. Falsifiable signature:
// VGPR_Count must finally exceed 128.
#define WLD(i) asm volatile("global_load_dwordx4 %0, %1, off offset:%2" \
    : "=v"(w##i) : "v"(wptr), "i"((i) * 16) : "memory");
#define W_DOT(i, acc) { float4 h4 = *(const float4*)&h_s[(i) * 4];              \
    acc = fmaf(w##i.x, h4.x, fmaf(w##i.y, h4.y,                                 \
          fmaf(w##i.z, h4.z, fmaf(w##i.w, h4.w, acc)))); }

__global__ __launch_bounds__(512)
void lstm_rec(const unsigned short* __restrict__ xg,   // [ROWS][1024]
              const float* __restrict__ Whh,           // [2][512][128]
              const int* __restrict__ lens,            // chunk-offset
              unsigned short* __restrict__ hs,         // [ROWS][256] or null
              float* __restrict__ hTf, float* __restrict__ hTb,
              int bOff)
{
    int dir = blockIdx.x >> 7;   // 128 batch per chunk
    int bl  = blockIdx.x & 127;
    int L   = lens[bl];
    int j   = threadIdx.x;

    __shared__ float h_s[HD];
    __shared__ float g_s[G4];

    const float* wptr = Whh + ((size_t)dir * G4 + j) * HD;
    float4 w0, w1, w2, w3, w4, w5, w6, w7, w8, w9, w10, w11, w12, w13, w14, w15;
    float4 w16, w17, w18, w19, w20, w21, w22, w23, w24, w25, w26, w27, w28, w29, w30, w31;
    WLD(0)  WLD(1)  WLD(2)  WLD(3)  WLD(4)  WLD(5)  WLD(6)  WLD(7)
    WLD(8)  WLD(9)  WLD(10) WLD(11) WLD(12) WLD(13) WLD(14) WLD(15)
    WLD(16) WLD(17) WLD(18) WLD(19) WLD(20) WLD(21) WLD(22) WLD(23)
    WLD(24) WLD(25) WLD(26) WLD(27) WLD(28) WLD(29) WLD(30) WLD(31)
    asm volatile("s_waitcnt vmcnt(0)" ::: "memory");

    if (j < HD) h_s[j] = 0.0f;
    float c = 0.0f;
    __syncthreads();

    size_t rowbase = (size_t)(bl * T_LEN) * 1024 + dir * G4 + j;
    int tt = dir ? (L - 1) : 0;
    float xcur = bf2f(xg[rowbase + (size_t)tt * 1024]);

    for (int t = 0; t < L; ++t) {
        // prefetch next step's xg; its L2 latency overlaps the dot product
        int t2  = (t + 1 < L) ? (t + 1) : t;
        int ttn = dir ? (L - 1 - t2) : t2;
        unsigned short xnraw = xg[rowbase + (size_t)ttn * 1024];

        float g0 = xcur, g1 = 0.0f, g2 = 0.0f, g3 = 0.0f;
        W_DOT(0,  g0) W_DOT(1,  g1) W_DOT(2,  g2) W_DOT(3,  g3)
        W_DOT(4,  g0) W_DOT(5,  g1) W_DOT(6,  g2) W_DOT(7,  g3)
        W_DOT(8,  g0) W_DOT(9,  g1) W_DOT(10, g2) W_DOT(11, g3)
        W_DOT(12, g0) W_DOT(13, g1) W_DOT(14, g2) W_DOT(15, g3)
        W_DOT(16, g0) W_DOT(17, g1) W_DOT(18, g2) W_DOT(19, g3)
        W_DOT(20, g0) W_DOT(21, g1) W_DOT(22, g2) W_DOT(23, g3)
        W_DOT(24, g0) W_DOT(25, g1) W_DOT(26, g2) W_DOT(27, g3)
        W_DOT(28, g0) W_DOT(29, g1) W_DOT(30, g2) W_DOT(31, g3)
        g_s[j] = (g0 + g1) + (g2 + g3);
        __syncthreads();
        if (j < HD) {
            float ig = sigf(g_s[j]);
            float fg = sigf(g_s[j + 128]);
            float gg = tanh_f(g_s[j + 256]);
            float og = sigf(g_s[j + 384]);
            c = fg * c + ig * gg;
            float hn = og * tanh_f(c);
            h_s[j] = hn;
            if (hs) hs[(size_t)(bl * T_LEN + tt) * 256 + dir * HD + j] = f2bf(hn);
        }
        __syncthreads();
        xcur = bf2f(xnraw);
        tt = ttn;
    }
    if (hTf && j < HD) {
        (dir ? hTb : hTf)[(size_t)(bOff + bl) * HD + j] = h_s[j];
    }
}

// ---------- final FC + log_softmax: h = [hT_b, hT_f] ----------
__global__ __launch_bounds__(256)
void fc_lsm(const float* __restrict__ hTf, const float* __restrict__ hTb,
            const float* __restrict__ Wfc, const float* __restrict__ bfc,
            float* __restrict__ out)
{
    int b = threadIdx.x;
    const float* hb = hTb + (size_t)b * HD;
    const float* hf = hTf + (size_t)b * HD;
    float l[NC];
#pragma unroll
    for (int cc = 0; cc < NC; ++cc) {
        const float* wr = Wfc + cc * 256;
        float acc = bfc[cc];
        for (int k = 0; k < HD; k += 4) {
            acc += hb[k] * wr[k] + hb[k + 1] * wr[k + 1]
                 + hb[k + 2] * wr[k + 2] + hb[k + 3] * wr[k + 3];
            acc += hf[k] * wr[128 + k] + hf[k + 1] * wr[128 + k + 1]
                 + hf[k + 2] * wr[128 + k + 2] + hf[k + 3] * wr[128 + k + 3];
        }
        l[cc] = acc;
    }
    float m = l[0];
#pragma unroll
    for (int cc = 1; cc < NC; ++cc) m = fmaxf(m, l[cc]);
    float s = 0.0f;
#pragma unroll
    for (int cc = 0; cc < NC; ++cc) s += __expf(l[cc] - m);
    float lg = m + logf(s);
#pragma unroll
    for (int cc = 0; cc < NC; ++cc) out[(size_t)b * NC + cc] = l[cc] - lg;
}

extern "C" void kernel_launch(void* const* d_in, const int* in_sizes, int n_in,
                              void* d_out, int out_size, void* d_ws, size_t ws_size,
                              hipStream_t stream)
{
    const float* X    = (const float*)d_in[0];
    const int*   len  = (const int*)d_in[1];
    const float* Wih0 = (const float*)d_in[2];   // (2,512,64)  -> (1024,64)
    const float* Whh0 = (const float*)d_in[3];   // (2,512,128)
    const float* b0   = (const float*)d_in[4];   // (2,512) -> (1024)
    const float* Wih1 = (const float*)d_in[5];   // (2,512,256) -> (1024,256)
    const float* Whh1 = (const float*)d_in[6];
    const float* b1   = (const float*)d_in[7];
    const float* Wfc  = (const float*)d_in[8];   // (12,256)
    const float* bfc  = (const float*)d_in[9];   // (12)
    float* out = (float*)d_out;

    char* ws = (char*)d_ws;
    unsigned short* xg = (unsigned short*)ws;                              // ROWS*1024 bf16
    unsigned short* h1 = (unsigned short*)(ws + (size_t)ROWS * 1024 * 2);  // ROWS*256 bf16
    float* hTf = (float*)(ws + (size_t)ROWS * 1024 * 2 + (size_t)ROWS * 256 * 2);
    float* hTb = hTf + (size_t)B_ALL * HD;

    dim3 blk(256);
    for (int ch = 0; ch < 2; ++ch) {
        const int* lc = len + ch * BCH;
        const float* Xc = X + (size_t)ch * BCH * T_LEN * D_INP;

        gates_gemm<float><<<dim3(ROWS / 128, 1024 / 128), blk, 0, stream>>>(
            Xc, Wih0, b0, lc, xg, D_INP);
        lstm_rec<<<2 * BCH, 512, 0, stream>>>(xg, Whh0, lc, h1, nullptr, nullptr, 0);
        gates_gemm<unsigned short><<<dim3(ROWS / 128, 1024 / 128), blk, 0, stream>>>(
            h1, Wih1, b1, lc, xg, 2 * HD);
        lstm_rec<<<2 * BCH, 512, 0, stream>>>(xg, Whh1, lc, nullptr, hTf, hTb, ch * BCH);
    }
    fc_lsm<<<1, 256, 0, stream>>>(hTf, hTb, Wfc, bfc, out);
}

// Round 6
// 3595.774 us; speedup vs baseline: 1.1081x; 1.0381x over previous
//
#include <hip/hip_runtime.h>
#include <hip/hip_bf16.h>
#include <cstdint>
#include <cstddef>

#define B_ALL 256
#define T_LEN 512
#define D_INP 64
#define HD    128
#define G4    512            // 4*H
#define NC    12
#define BCH   128            // batch per chunk
#define ROWS  (BCH * T_LEN)  // 65536 rows per chunk

// ---------- helpers ----------
__device__ __forceinline__ float bf2f(unsigned short u) {
    union { unsigned int i; float f; } v; v.i = ((unsigned int)u) << 16; return v.f;
}
__device__ __forceinline__ unsigned short f2bf(float f) {
    union { float f; unsigned int i; } v; v.f = f;
    unsigned int r = v.i + 0x7FFFu + ((v.i >> 16) & 1u);  // round-nearest-even
    return (unsigned short)(r >> 16);
}
__device__ __forceinline__ float sigf(float x) { return 1.0f / (1.0f + __expf(-x)); }
__device__ __forceinline__ float tanh_f(float x) {
    float xx = fminf(15.0f, fmaxf(-15.0f, x));
    float e = __expf(2.0f * xx);
    return (e - 1.0f) / (e + 1.0f);
}

__device__ __forceinline__ float4 loadA4(const float* p) { return *(const float4*)p; }
__device__ __forceinline__ float4 loadA4(const unsigned short* p) {
    ushort4 u = *(const ushort4*)p;  // 8B aligned
    return make_float4(bf2f(u.x), bf2f(u.y), bf2f(u.z), bf2f(u.w));
}

// ---------- gates GEMM: out[r][c] = bias[c] + sum_k A[r][k] * W[c][k] ----------
template <typename TA>
__global__ __launch_bounds__(256)
void gates_gemm(const TA* __restrict__ A, const float* __restrict__ W,
                const float* __restrict__ bias, const int* __restrict__ lens,
                unsigned short* __restrict__ out, int K)
{
    int row0 = blockIdx.x * 128;
    int col0 = blockIdx.y * 128;
    int bl = row0 >> 9;            // T_LEN = 512 rows per batch element
    int t0 = row0 & (T_LEN - 1);
    if (t0 >= lens[bl]) return;    // whole tile masked -> never read downstream

    __shared__ float As[32][130];
    __shared__ float Bs[32][130];

    int tid = threadIdx.x;
    int tx = tid & 15;
    int ty = tid >> 4;
    int lr = tid >> 3;
    int lk = (tid & 7) * 4;

    float acc[8][8];
#pragma unroll
    for (int i = 0; i < 8; ++i)
#pragma unroll
        for (int j = 0; j < 8; ++j) acc[i][j] = 0.0f;

    for (int kt = 0; kt < K; kt += 32) {
#pragma unroll
        for (int rr = 0; rr < 128; rr += 32) {
            int r = rr + lr;
            float4 v = loadA4(A + (size_t)(row0 + r) * K + kt + lk);
            As[lk + 0][r] = v.x; As[lk + 1][r] = v.y;
            As[lk + 2][r] = v.z; As[lk + 3][r] = v.w;
        }
#pragma unroll
        for (int rr = 0; rr < 128; rr += 32) {
            int c = rr + lr;
            float4 v = *(const float4*)(W + (size_t)(col0 + c) * K + kt + lk);
            Bs[lk + 0][c] = v.x; Bs[lk + 1][c] = v.y;
            Bs[lk + 2][c] = v.z; Bs[lk + 3][c] = v.w;
        }
        __syncthreads();
#pragma unroll 8
        for (int kk = 0; kk < 32; ++kk) {
            float a[8], b[8];
#pragma unroll
            for (int q = 0; q < 4; ++q) {
                float2 t = *(const float2*)&As[kk][ty * 8 + 2 * q];
                a[2 * q] = t.x; a[2 * q + 1] = t.y;
                float2 u = *(const float2*)&Bs[kk][tx * 8 + 2 * q];
                b[2 * q] = u.x; b[2 * q + 1] = u.y;
            }
#pragma unroll
            for (int i = 0; i < 8; ++i)
#pragma unroll
                for (int j = 0; j < 8; ++j) acc[i][j] += a[i] * b[j];
        }
        __syncthreads();
    }

    float bj[8];
#pragma unroll
    for (int j = 0; j < 8; ++j) bj[j] = bias[col0 + tx * 8 + j];
#pragma unroll
    for (int i = 0; i < 8; ++i) {
        size_t base = (size_t)(row0 + ty * 8 + i) * 1024 + col0 + tx * 8;
        ushort4 p0, p1;
        p0.x = f2bf(acc[i][0] + bj[0]); p0.y = f2bf(acc[i][1] + bj[1]);
        p0.z = f2bf(acc[i][2] + bj[2]); p0.w = f2bf(acc[i][3] + bj[3]);
        p1.x = f2bf(acc[i][4] + bj[4]); p1.y = f2bf(acc[i][5] + bj[5]);
        p1.z = f2bf(acc[i][6] + bj[6]); p1.w = f2bf(acc[i][7] + bj[7]);
        *(ushort4*)&out[base] = p0;
        *(ushort4*)&out[base + 4] = p1;
    }
}

// ---------- LSTM recurrence: one block per (dir, batch-element) ----------
// R5 post-mortem completes the diagnosis:
//  * Plain loads (R1-R4): trivially REMATERIALIZABLE -> spiller re-executes
//    them in-loop at zero modeled cost, at ANY VGPR budget (even 32 live).
//  * asm-volatile loads w/o budget (R5): not remat-able -> genuine scratch
//    spill/fill (default budget ~88 VGPR); scratch working set 16MB/XCD >>
//    4MB L2 -> the 37.7GB FETCH goes to HBM.
// Never tested together: non-remat loads + explicit budget. waves_per_eu(2,2)
// => 256-VGPR budget, fits ~170 live, still 2 waves/SIMD.
// Falsifiable: VGPR_Count >= 160 and FETCH < 1GB, else approach is dead.
#define WLD(i) asm volatile("global_load_dwordx4 %0, %1, off offset:%2" \
    : "=v"(w##i) : "v"(wptr), "i"((i) * 16) : "memory");
#define W_DOT(i, acc) { float4 h4 = *(const float4*)&h_s[(i) * 4];              \
    acc = fmaf(w##i.x, h4.x, fmaf(w##i.y, h4.y,                                 \
          fmaf(w##i.z, h4.z, fmaf(w##i.w, h4.w, acc)))); }

__global__ __attribute__((amdgpu_flat_work_group_size(512, 512),
                          amdgpu_waves_per_eu(2, 2)))
void lstm_rec(const unsigned short* __restrict__ xg,   // [ROWS][1024]
              const float* __restrict__ Whh,           // [2][512][128]
              const int* __restrict__ lens,            // chunk-offset
              unsigned short* __restrict__ hs,         // [ROWS][256] or null
              float* __restrict__ hTf, float* __restrict__ hTb,
              int bOff)
{
    int dir = blockIdx.x >> 7;   // 128 batch per chunk
    int bl  = blockIdx.x & 127;
    int L   = lens[bl];
    int j   = threadIdx.x;

    __shared__ float h_s[HD];
    __shared__ float g_s[G4];

    const float* wptr = Whh + ((size_t)dir * G4 + j) * HD;
    float4 w0, w1, w2, w3, w4, w5, w6, w7, w8, w9, w10, w11, w12, w13, w14, w15;
    float4 w16, w17, w18, w19, w20, w21, w22, w23, w24, w25, w26, w27, w28, w29, w30, w31;
    WLD(0)  WLD(1)  WLD(2)  WLD(3)  WLD(4)  WLD(5)  WLD(6)  WLD(7)
    WLD(8)  WLD(9)  WLD(10) WLD(11) WLD(12) WLD(13) WLD(14) WLD(15)
    WLD(16) WLD(17) WLD(18) WLD(19) WLD(20) WLD(21) WLD(22) WLD(23)
    WLD(24) WLD(25) WLD(26) WLD(27) WLD(28) WLD(29) WLD(30) WLD(31)
    asm volatile("s_waitcnt vmcnt(0)" ::: "memory");

    if (j < HD) h_s[j] = 0.0f;
    float c = 0.0f;
    __syncthreads();

    size_t rowbase = (size_t)(bl * T_LEN) * 1024 + dir * G4 + j;
    int tt = dir ? (L - 1) : 0;
    float xcur = bf2f(xg[rowbase + (size_t)tt * 1024]);

    for (int t = 0; t < L; ++t) {
        // prefetch next step's xg; its L2 latency overlaps the dot product
        int t2  = (t + 1 < L) ? (t + 1) : t;
        int ttn = dir ? (L - 1 - t2) : t2;
        unsigned short xnraw = xg[rowbase + (size_t)ttn * 1024];

        float g0 = xcur, g1 = 0.0f, g2 = 0.0f, g3 = 0.0f;
        W_DOT(0,  g0) W_DOT(1,  g1) W_DOT(2,  g2) W_DOT(3,  g3)
        W_DOT(4,  g0) W_DOT(5,  g1) W_DOT(6,  g2) W_DOT(7,  g3)
        W_DOT(8,  g0) W_DOT(9,  g1) W_DOT(10, g2) W_DOT(11, g3)
        W_DOT(12, g0) W_DOT(13, g1) W_DOT(14, g2) W_DOT(15, g3)
        W_DOT(16, g0) W_DOT(17, g1) W_DOT(18, g2) W_DOT(19, g3)
        W_DOT(20, g0) W_DOT(21, g1) W_DOT(22, g2) W_DOT(23, g3)
        W_DOT(24, g0) W_DOT(25, g1) W_DOT(26, g2) W_DOT(27, g3)
        W_DOT(28, g0) W_DOT(29, g1) W_DOT(30, g2) W_DOT(31, g3)
        g_s[j] = (g0 + g1) + (g2 + g3);
        __syncthreads();
        if (j < HD) {
            float ig = sigf(g_s[j]);
            float fg = sigf(g_s[j + 128]);
            float gg = tanh_f(g_s[j + 256]);
            float og = sigf(g_s[j + 384]);
            c = fg * c + ig * gg;
            float hn = og * tanh_f(c);
            h_s[j] = hn;
            if (hs) hs[(size_t)(bl * T_LEN + tt) * 256 + dir * HD + j] = f2bf(hn);
        }
        __syncthreads();
        xcur = bf2f(xnraw);
        tt = ttn;
    }
    if (hTf && j < HD) {
        (dir ? hTb : hTf)[(size_t)(bOff + bl) * HD + j] = h_s[j];
    }
}

// ---------- final FC + log_softmax: h = [hT_b, hT_f] ----------
__global__ __launch_bounds__(256)
void fc_lsm(const float* __restrict__ hTf, const float* __restrict__ hTb,
            const float* __restrict__ Wfc, const float* __restrict__ bfc,
            float* __restrict__ out)
{
    int b = threadIdx.x;
    const float* hb = hTb + (size_t)b * HD;
    const float* hf = hTf + (size_t)b * HD;
    float l[NC];
#pragma unroll
    for (int cc = 0; cc < NC; ++cc) {
        const float* wr = Wfc + cc * 256;
        float acc = bfc[cc];
        for (int k = 0; k < HD; k += 4) {
            acc += hb[k] * wr[k] + hb[k + 1] * wr[k + 1]
                 + hb[k + 2] * wr[k + 2] + hb[k + 3] * wr[k + 3];
            acc += hf[k] * wr[128 + k] + hf[k + 1] * wr[128 + k + 1]
                 + hf[k + 2] * wr[128 + k + 2] + hf[k + 3] * wr[128 + k + 3];
        }
        l[cc] = acc;
    }
    float m = l[0];
#pragma unroll
    for (int cc = 1; cc < NC; ++cc) m = fmaxf(m, l[cc]);
    float s = 0.0f;
#pragma unroll
    for (int cc = 0; cc < NC; ++cc) s += __expf(l[cc] - m);
    float lg = m + logf(s);
#pragma unroll
    for (int cc = 0; cc < NC; ++cc) out[(size_t)b * NC + cc] = l[cc] - lg;
}

extern "C" void kernel_launch(void* const* d_in, const int* in_sizes, int n_in,
                              void* d_out, int out_size, void* d_ws, size_t ws_size,
                              hipStream_t stream)
{
    const float* X    = (const float*)d_in[0];
    const int*   len  = (const int*)d_in[1];
    const float* Wih0 = (const float*)d_in[2];   // (2,512,64)  -> (1024,64)
    const float* Whh0 = (const float*)d_in[3];   // (2,512,128)
    const float* b0   = (const float*)d_in[4];   // (2,512) -> (1024)
    const float* Wih1 = (const float*)d_in[5];   // (2,512,256) -> (1024,256)
    const float* Whh1 = (const float*)d_in[6];
    const float* b1   = (const float*)d_in[7];
    const float* Wfc  = (const float*)d_in[8];   // (12,256)
    const float* bfc  = (const float*)d_in[9];   // (12)
    float* out = (float*)d_out;

    char* ws = (char*)d_ws;
    unsigned short* xg = (unsigned short*)ws;                              // ROWS*1024 bf16
    unsigned short* h1 = (unsigned short*)(ws + (size_t)ROWS * 1024 * 2);  // ROWS*256 bf16
    float* hTf = (float*)(ws + (size_t)ROWS * 1024 * 2 + (size_t)ROWS * 256 * 2);
    float* hTb = hTf + (size_t)B_ALL * HD;

    dim3 blk(256);
    for (int ch = 0; ch < 2; ++ch) {
        const int* lc = len + ch * BCH;
        const float* Xc = X + (size_t)ch * BCH * T_LEN * D_INP;

        gates_gemm<float><<<dim3(ROWS / 128, 1024 / 128), blk, 0, stream>>>(
            Xc, Wih0, b0, lc, xg, D_INP);
        lstm_rec<<<2 * BCH, 512, 0, stream>>>(xg, Whh0, lc, h1, nullptr, nullptr, 0);
        gates_gemm<unsigned short><<<dim3(ROWS / 128, 1024 / 128), blk, 0, stream>>>(
            h1, Wih1, b1, lc, xg, 2 * HD);
        lstm_rec<<<2 * BCH, 512, 0, stream>>>(xg, Whh1, lc, nullptr, hTf, hTb, ch * BCH);
    }
    fc_lsm<<<1, 256, 0, stream>>>(hTf, hTb, Wfc, bfc, out);
}